// Round 8
// baseline (14862.869 us; speedup 1.0000x reference)
//
#include <hip/hip_runtime.h>
#include <cstdint>
#include <cstddef>

typedef _Float16 half_t;
typedef _Float16 half2_t __attribute__((ext_vector_type(2)));
typedef _Float16 half8_t __attribute__((ext_vector_type(8)));
typedef float   float4_t __attribute__((ext_vector_type(4)));

#define L_N 2
#define B_N 32
#define S_N 2048
#define H_N 256
#define G_N 1024            // 4H
#define M_N (B_N*S_N)       // 65536

// ---- pipelined per-chain geometry ----
// 128 blocks = 32 chains x 4 roles. Role 0 (A): layer-0 recurrence (whole
// chain on ONE CU -> serial path intra-CU). Roles 1,2 (B0,B1): xp1 = Wi1.h0+b,
// feed-forward with slack. Role 3 (C): layer-1 recurrence.
// r8 changes vs r7: (1) hysteresis credit checks (burst R/2 steps per credit
// read, amortizing the ~1800cy RTT that r7 paid EVERY step once rings filled);
// (2) B prefetches next ring slot during compute; (3) builtin fdot2 (no
// arch-VGPR pinning -> allocator free to use unified VGPR/AGPR file).
#define RH 64                // h0 ring slots (A->B)
#define RX 64                // xp1 ring slots (B->C)

// ws layout (bytes)
#define WS_A0    0ull        // fp16 [M][H] layer-0 input; head reused for comm
                             // rings AFTER gemm_xp consumed it (stream-ordered)
#define WS_XP    33554432ull // fp16 [M][G] layer-0 input projection [m][cell][4]
#define WS_WI    167772160ull
#define WS_WH    168820736ull
#define WS_BSUM  169869312ull
// comm region (inside dead A0):
#define WS_RH_OFF 0ull                   // u64 ringH[32][RH][128]   = 2 MiB
#define WS_RX_OFF 2097152ull             // u64 ringX[32][RX][1024]  = 16 MiB
#define WS_PG_OFF 18874368ull            // u32 bprog[64]; u32 cprog[32]
#define WS_COMM_BYTES (18874368ull + 4096ull)

// dynamic LDS layout for lstm_pipe
#define SM_WLDS 0            // uint4 [16][512] = 128 KiB (A/C weight tail)
#define SM_HBUF 131072       // u32 [2][128] h pairs (B reuses [0] for h0 stage)
#define SM_RED  132096       // f32 [4][256] partial sums (B uses as f32[2][256])
#define SM_XG   136192       // u32 [2][256] C's polled f,o gate bits
#define SMEM_P  138240

__global__ void cvt_f32_f16(const float* __restrict__ in, half_t* __restrict__ out, int n){
  int i = blockIdx.x*256 + threadIdx.x;
  if (i < n) out[i] = (half_t)in[i];
}

__global__ void make_bsum(const float* __restrict__ bi, const float* __restrict__ bh,
                          float* __restrict__ bs, int n){
  int i = blockIdx.x*256 + threadIdx.x;
  if (i < n) bs[i] = bi[i] + bh[i];
}

// XP[m, cell, gate] = sum_k A[m,k] * W[gate*256+cell, k] + bsum[...]
__global__ __launch_bounds__(256) void gemm_xp(
    const half_t* __restrict__ A, const half_t* __restrict__ W,
    const float* __restrict__ bsum, half_t* __restrict__ XP)
{
  const int wave = threadIdx.x >> 6;
  const int lane = threadIdx.x & 63;
  const int l15 = lane & 15, quad = lane >> 4;
  const int m0 = blockIdx.x*64 + wave*16;
  const int n0 = blockIdx.y*64;
  float4_t acc[4] = {{0,0,0,0},{0,0,0,0},{0,0,0,0},{0,0,0,0}};
  const half_t* arow = A + (size_t)(m0 + l15)*H_N + quad*8;
  const half_t* brow[4];
  #pragma unroll
  for (int nt=0; nt<4; ++nt)
    brow[nt] = W + (size_t)(n0 + nt*16 + l15)*H_N + quad*8;
  #pragma unroll
  for (int k0=0; k0<H_N; k0+=32){
    half8_t af = *(const half8_t*)(arow + k0);
    #pragma unroll
    for (int nt=0; nt<4; ++nt){
      half8_t bf = *(const half8_t*)(brow[nt] + k0);
      acc[nt] = __builtin_amdgcn_mfma_f32_16x16x32_f16(af, bf, acc[nt], 0, 0, 0);
    }
  }
  #pragma unroll
  for (int nt=0; nt<4; ++nt){
    const int col = n0 + nt*16 + l15;
    const int cell = col & 255, gate = col >> 8;
    const float bs = bsum[col];
    #pragma unroll
    for (int r=0; r<4; ++r){
      XP[(size_t)(m0 + quad*4 + r)*G_N + cell*4 + gate] = (half_t)(acc[nt][r] + bs);
    }
  }
}

__device__ __forceinline__ float sigf(float x){ return 1.f/(1.f + __expf(-x)); }
__device__ __forceinline__ float tanh_f(float x){ return 1.f - 2.f/(__expf(2.f*x) + 1.f); }

__device__ __forceinline__ unsigned long long ld64a(unsigned long long* p){
  return __hip_atomic_load(p, __ATOMIC_RELAXED, __HIP_MEMORY_SCOPE_AGENT);
}
__device__ __forceinline__ void st64a(unsigned long long* p, unsigned long long v){
  __hip_atomic_store(p, v, __ATOMIC_RELAXED, __HIP_MEMORY_SCOPE_AGENT);
}
__device__ __forceinline__ unsigned ld32a(unsigned* p){
  return __hip_atomic_load(p, __ATOMIC_RELAXED, __HIP_MEMORY_SCOPE_AGENT);
}
__device__ __forceinline__ void st32a(unsigned* p, unsigned v){
  __hip_atomic_store(p, v, __ATOMIC_RELAXED, __HIP_MEMORY_SCOPE_AGENT);
}

__device__ __forceinline__ void dot2(float& a, uint32_t w, uint32_t h){
  a = __builtin_amdgcn_fdot2(__builtin_bit_cast(half2_t, w),
                             __builtin_bit_cast(half2_t, h), a, false);
}

// Raw LDS-only barrier (no vmcnt drain of in-flight global ops) - r4 proven.
__device__ __forceinline__ void wg_barrier_lds(){
  asm volatile("s_waitcnt lgkmcnt(0)" ::: "memory");
  __builtin_amdgcn_s_barrier();
  asm volatile("" ::: "memory");
}

// 512 threads, 1 block/CU (138KB LDS). j = tid&255 (cell), kh = tid>>8 (K-half).
__global__ __launch_bounds__(512,2) __attribute__((amdgpu_waves_per_eu(2,2)))
void lstm_pipe(
    const uint32_t* __restrict__ Wh0p,  // fp16-pair view [1024][128]
    const uint32_t* __restrict__ Wh1p,
    const uint32_t* __restrict__ Wi1p,
    const half_t*  __restrict__ xp,     // [M][1024] packed [m][cell][4], biases folded
    const float*   __restrict__ bsum1,  // [1024] layer-1 bias sums
    unsigned long long* __restrict__ ringH,
    unsigned long long* __restrict__ ringX,
    unsigned* __restrict__ bprog, unsigned* __restrict__ cprog,
    float* __restrict__ out, float* __restrict__ hT, float* __restrict__ cT)
{
  extern __shared__ unsigned char smem[];
  uint4*    wlds = (uint4*)(smem + SM_WLDS);
  uint32_t* hbuf = (uint32_t*)(smem + SM_HBUF);
  float*    redf = (float*)(smem + SM_RED);
  uint32_t* xg   = (uint32_t*)(smem + SM_XG);

  const int tid = threadIdx.x;
  const int j   = tid & 255;
  const int kh  = tid >> 8;
  const int lw  = tid & 63;
  const int chain = blockIdx.x & 31;
  const int role  = blockIdx.x >> 5;     // 0=A, 1=B0, 2=B1, 3=C
  const size_t base = (size_t)chain * S_N;

  unsigned long long* rH = ringH + (size_t)chain * (RH*128);
  unsigned long long* rX = ringX + (size_t)chain * (RX*1024);

  if (role == 1 || role == 2){
    // ================= B: xp1 rows {gbase*256+j, (gbase+1)*256+j} =================
    const int gbase = (role == 1) ? 0 : 2;
    uint32_t w0[64], w1[64];
    {
      const uint32_t* p0 = Wi1p + (size_t)((gbase  )*256 + j)*128 + kh*64;
      const uint32_t* p1 = Wi1p + (size_t)((gbase+1)*256 + j)*128 + kh*64;
      #pragma unroll
      for (int i=0;i<64;++i){ w0[i] = p0[i]; w1[i] = p1[i]; }
    }
    float bs0 = 0.f, bs1 = 0.f;
    if (!kh){ bs0 = bsum1[gbase*256 + j]; bs1 = bsum1[(gbase+1)*256 + j]; }
    unsigned* myprog = bprog + (role-1)*32 + chain;
    unsigned* cp = cprog + chain;
    int cseen = 0;
    unsigned long long vpre = 0ull;      // prefetched next-slot value
    for (int t=0; t<S_N; ++t){
      // hysteresis credit on C: when blocked, wait until C within RX/2 ->
      // next RX/2 steps are check-free (amortizes the credit-read RTT)
      if (!kh && t >= RX && cseen < t - RX + 1){
        const int target = t - RX/2;
        do { cseen = (int)ld32a(cp); } while (cseen < target);
      }
      if (tid < 128){
        unsigned long long* ph = rH + (size_t)(t & (RH-1))*128 + tid;
        unsigned long long v = vpre;     // usually already holds slot t's value
        while ((unsigned)(v >> 32) != (unsigned)(t+1)) v = ld64a(ph);
        hbuf[tid] = (uint32_t)v;
      }
      wg_barrier_lds();
      if (tid == 0) st32a(myprog, (unsigned)(t+1));   // slot t consumed
      if (tid < 128 && t+1 < S_N)        // prefetch next slot; latency hides
        vpre = ld64a(rH + (size_t)((t+1) & (RH-1))*128 + tid);
      const uint4* h4 = (const uint4*)(hbuf + kh*64); // wave-uniform broadcasts
      float a0 = 0.f, a1 = 0.f;
      #pragma unroll
      for (int i=0;i<16;++i){
        const uint4 hh = h4[i];
        dot2(a0, w0[4*i+0], hh.x); dot2(a1, w1[4*i+0], hh.x);
        dot2(a0, w0[4*i+1], hh.y); dot2(a1, w1[4*i+1], hh.y);
        dot2(a0, w0[4*i+2], hh.z); dot2(a1, w1[4*i+2], hh.z);
        dot2(a0, w0[4*i+3], hh.w); dot2(a1, w1[4*i+3], hh.w);
      }
      if (kh){ redf[2*j] = a0; redf[2*j+1] = a1; }
      wg_barrier_lds();
      if (!kh){
        const float s0 = a0 + redf[2*j]   + bs0;
        const float s1 = a1 + redf[2*j+1] + bs1;
        unsigned long long* q = rX + (size_t)(t & (RX-1))*1024;
        const unsigned long long tg = (unsigned long long)(unsigned)(t+1) << 32;
        st64a(q + (gbase  )*256 + j, tg | (unsigned long long)__builtin_bit_cast(unsigned, s0));
        st64a(q + (gbase+1)*256 + j, tg | (unsigned long long)__builtin_bit_cast(unsigned, s1));
      }
    }
    return;
  }

  // ================= A (role 0) / C (role 3): intra-CU recurrence =================
  const bool isA = (role == 0);
  const uint32_t* mat = isA ? Wh0p : Wh1p;
  uint32_t wreg[4][48];
  #pragma unroll
  for (int q=0;q<4;++q){
    const uint32_t* wp = mat + (size_t)(q*256 + j)*128 + kh*64;
    #pragma unroll
    for (int k=0;k<48;++k) wreg[q][k] = wp[k];
  }
  { // LDS weight tail: pairs kh*64+48+k, 4 gates packed per uint4
    const uint32_t* q0 = mat + (size_t)(  0 + j)*128 + kh*64 + 48;
    const uint32_t* q1 = mat + (size_t)(256 + j)*128 + kh*64 + 48;
    const uint32_t* q2 = mat + (size_t)(512 + j)*128 + kh*64 + 48;
    const uint32_t* q3 = mat + (size_t)(768 + j)*128 + kh*64 + 48;
    #pragma unroll
    for (int k=0;k<16;++k){
      uint4 v; v.x=q0[k]; v.y=q1[k]; v.z=q2[k]; v.w=q3[k];
      wlds[k*512 + tid] = v;
    }
  }
  if (tid < 128) hbuf[tid] = 0u;    // h(-1) = 0 in read buffer of t=0
  float cst = 0.f;
  int bseen = 0;
  unsigned* bp0 = bprog + chain;
  unsigned* bp1 = bprog + 32 + chain;
  wg_barrier_lds();

  for (int t=0; t<S_N; ++t){
    const int rb = t & 1, wb = rb ^ 1;
    const unsigned tagx = (unsigned)(t+1);
    uint2 xv = {0u,0u};
    unsigned long long va = 0, vb = 0;
    unsigned long long *qa = nullptr, *qb = nullptr;
    if (isA){
      if (!kh) xv = *(const uint2*)(xp + (base + t)*G_N + (size_t)j*4);
    } else {
      qa = rX + (size_t)(t & (RX-1))*1024 + tid;      // gates {i (kh0) | f (kh1)}
      qb = qa + 512;                                   // gates {g (kh0) | o (kh1)}
      va = ld64a(qa); vb = ld64a(qb);                  // in flight across matvec
    }

    // matvec: 4 gate rows x 64 K-pairs; h reads are wave-uniform broadcasts
    const uint4* hr4 = (const uint4*)(hbuf + rb*128 + kh*64);
    float a0=0.f, a1=0.f, a2=0.f, a3=0.f;
    #pragma unroll
    for (int k8=0;k8<12;++k8){
      const uint4 hh = hr4[k8];
      dot2(a0,wreg[0][k8*4+0],hh.x); dot2(a1,wreg[1][k8*4+0],hh.x); dot2(a2,wreg[2][k8*4+0],hh.x); dot2(a3,wreg[3][k8*4+0],hh.x);
      dot2(a0,wreg[0][k8*4+1],hh.y); dot2(a1,wreg[1][k8*4+1],hh.y); dot2(a2,wreg[2][k8*4+1],hh.y); dot2(a3,wreg[3][k8*4+1],hh.y);
      dot2(a0,wreg[0][k8*4+2],hh.z); dot2(a1,wreg[1][k8*4+2],hh.z); dot2(a2,wreg[2][k8*4+2],hh.z); dot2(a3,wreg[3][k8*4+2],hh.z);
      dot2(a0,wreg[0][k8*4+3],hh.w); dot2(a1,wreg[1][k8*4+3],hh.w); dot2(a2,wreg[2][k8*4+3],hh.w); dot2(a3,wreg[3][k8*4+3],hh.w);
    }
    #pragma unroll
    for (int k8=0;k8<4;++k8){
      const uint4 hh = hr4[12+k8];
      { const uint4 w = wlds[(k8*4+0)*512+tid]; dot2(a0,w.x,hh.x); dot2(a1,w.y,hh.x); dot2(a2,w.z,hh.x); dot2(a3,w.w,hh.x); }
      { const uint4 w = wlds[(k8*4+1)*512+tid]; dot2(a0,w.x,hh.y); dot2(a1,w.y,hh.y); dot2(a2,w.z,hh.y); dot2(a3,w.w,hh.y); }
      { const uint4 w = wlds[(k8*4+2)*512+tid]; dot2(a0,w.x,hh.z); dot2(a1,w.y,hh.z); dot2(a2,w.z,hh.z); dot2(a3,w.w,hh.z); }
      { const uint4 w = wlds[(k8*4+3)*512+tid]; dot2(a0,w.x,hh.w); dot2(a1,w.y,hh.w); dot2(a2,w.z,hh.w); dot2(a3,w.w,hh.w); }
    }

    if (!isA){
      while ((unsigned)(va >> 32) != tagx) va = ld64a(qa);
      while ((unsigned)(vb >> 32) != tagx) vb = ld64a(qb);
    }
    if (kh){
      float4* r4 = (float4*)redf; r4[j] = make_float4(a0,a1,a2,a3);
      if (!isA){ xg[j] = (uint32_t)va; xg[256 + j] = (uint32_t)vb; }
    }
    wg_barrier_lds();                 // partials (+xg) visible

    if (!kh){
      const float4 rr = ((float4*)redf)[j];
      float s0, s1, s2, s3;
      if (isA){
        const half2_t xlo = __builtin_bit_cast(half2_t, xv.x);
        const half2_t xhi = __builtin_bit_cast(half2_t, xv.y);
        s0 = a0 + rr.x + (float)xlo.x;
        s1 = a1 + rr.y + (float)xlo.y;
        s2 = a2 + rr.z + (float)xhi.x;
        s3 = a3 + rr.w + (float)xhi.y;
      } else {
        s0 = a0 + rr.x + __builtin_bit_cast(float, (unsigned)va);
        s1 = a1 + rr.y + __builtin_bit_cast(float, xg[j]);
        s2 = a2 + rr.z + __builtin_bit_cast(float, (unsigned)vb);
        s3 = a3 + rr.w + __builtin_bit_cast(float, xg[256 + j]);
      }
      const float gi = sigf(s0);
      const float gf = sigf(s1);
      const float gg = tanh_f(s2);
      const float go = sigf(s3);
      cst = gf*cst + gi*gg;
      const float h = go * tanh_f(cst);
      const half_t hv16 = (half_t)h;
      const unsigned short hu16 = __builtin_bit_cast(unsigned short, hv16);
      ((unsigned short*)hbuf)[wb*256 + j] = hu16;     // next step's h source

      if (isA){
        const int hu = (int)hu16;
        const int plo = __shfl(hu, 2*(lw & 31),     64);
        const int phi = __shfl(hu, 2*(lw & 31) + 1, 64);
        // hysteresis credit on B: when blocked, wait until min(B0,B1) within
        // RH/2 -> next RH/2 publishes are check-free
        if (t >= RH && bseen < t - RH + 1){
          const int target = t - RH/2;
          do {
            const int x0 = (int)ld32a(bp0);
            const int x1 = (int)ld32a(bp1);
            bseen = x0 < x1 ? x0 : x1;
          } while (bseen < target);
        }
        if (lw < 32){
          const unsigned long long val =
              ((unsigned long long)(unsigned)(t+1) << 32)
            | (unsigned long long)((((unsigned)phi & 0xffffu) << 16) | ((unsigned)plo & 0xffffu));
          st64a(rH + (size_t)(t & (RH-1))*128 + (j >> 6)*32 + lw, val);
        }
        if (t == S_N-1){ hT[chain*H_N + j] = h; cT[chain*H_N + j] = cst; }
      } else {
        out[(base + t)*H_N + j] = h;
        if (j == 0) st32a(cprog + chain, (unsigned)(t+1));
        if (t == S_N-1){ hT[B_N*H_N + chain*H_N + j] = h; cT[B_N*H_N + chain*H_N + j] = cst; }
      }
    }
    wg_barrier_lds();                 // hbuf[wb] visible; WAR on redf/xg
  }
}

extern "C" void kernel_launch(void* const* d_in, const int* in_sizes, int n_in,
                              void* d_out, int out_size, void* d_ws, size_t ws_size,
                              hipStream_t stream)
{
  const float* x   = (const float*)d_in[0];
  const float* Wih = (const float*)d_in[1];
  const float* bih = (const float*)d_in[2];
  const float* Whh = (const float*)d_in[3];
  const float* bhh = (const float*)d_in[4];
  float* out = (float*)d_out;

  char* ws = (char*)d_ws;
  half_t* A0   = (half_t*)(ws + WS_A0);
  half_t* XP   = (half_t*)(ws + WS_XP);
  half_t* Wi16 = (half_t*)(ws + WS_WI);
  half_t* Wh16 = (half_t*)(ws + WS_WH);
  float*  bsum = (float*)(ws + WS_BSUM);
  unsigned long long* ringH = (unsigned long long*)(ws + WS_RH_OFF);
  unsigned long long* ringX = (unsigned long long*)(ws + WS_RX_OFF);
  unsigned* bprog = (unsigned*)(ws + WS_PG_OFF);
  unsigned* cprog = bprog + 64;

  cvt_f32_f16<<<dim3(M_N*H_N/256), dim3(256), 0, stream>>>(x, A0, M_N*H_N);
  cvt_f32_f16<<<dim3(L_N*G_N*H_N/256), dim3(256), 0, stream>>>(Wih, Wi16, L_N*G_N*H_N);
  cvt_f32_f16<<<dim3(L_N*G_N*H_N/256), dim3(256), 0, stream>>>(Whh, Wh16, L_N*G_N*H_N);
  make_bsum<<<dim3(L_N*G_N/256), dim3(256), 0, stream>>>(bih, bhh, bsum, L_N*G_N);

  float* hT = out + (size_t)M_N*H_N;       // hs [2][32][256]
  float* cT = hT + (size_t)L_N*B_N*H_N;    // cs [2][32][256]

  // layer-0 input projection (reads A0) BEFORE rings overwrite the A0 region
  gemm_xp<<<dim3(M_N/64, G_N/64), dim3(256), 0, stream>>>(A0, Wi16, bsum, XP);

  hipMemsetAsync(ws, 0, WS_COMM_BYTES, stream);   // rings + progress counters

  lstm_pipe<<<dim3(128), dim3(512), SMEM_P, stream>>>(
      (const uint32_t*)Wh16,
      (const uint32_t*)(Wh16 + (size_t)G_N*H_N),
      (const uint32_t*)(Wi16 + (size_t)G_N*H_N),
      XP, bsum + G_N, ringH, ringX, bprog, cprog, out, hT, cT);
}

// Round 10
// 7320.836 us; speedup vs baseline: 2.0302x; 2.0302x over previous
//
#include <hip/hip_runtime.h>
#include <cstdint>
#include <cstddef>

typedef _Float16 half_t;
typedef _Float16 half2_t __attribute__((ext_vector_type(2)));
typedef _Float16 half8_t __attribute__((ext_vector_type(8)));
typedef float   float4_t __attribute__((ext_vector_type(4)));

#define L_N 2
#define B_N 32
#define S_N 2048
#define H_N 256
#define G_N 1024            // 4H
#define M_N (B_N*S_N)       // 65536

// ---- fused recurrence, wave-owned cells (r10) ----
// 256 blocks = 32 chains x 8 cell-slices; iteration t advances layer0 step t
// and layer1 step t-1. 12 waves/block:
//   waves 0-3  = L0: 8 cells each; lane = c_loc*8 + gate*2 + khalf
//   waves 4-11 = L1: 4 cells each; lane = c_loc*16 + gate*4 + kquarter,
//                K = [Wh1.h1 (kq 0,1) | Wi1.h0 (kq 2,3)]
// Per-cell reduce is wave-internal (shfl_xor + 3 gather shfl): NO red[] LDS
// round-trip, NO second barrier; finisher lanes (8/wave L0, 4/wave L1) run
// activations in parallel and publish immediately -> publish leaves ~600cy
// earlier than r4's serial 32-lane finisher.
// Exchange primitives = r4-proven relaxed agent atomics (NO inline-asm polls;
// r9's asm poll raced). Ring atom = u32 {tag16 | h fp16}; own cells go via
// LDS directly (never through the global ring).
#define RING_R 4
#define RING_BYTES (B_N*RING_R*256*4)   // 128 KiB per ring

// ws layout (bytes)
#define WS_A0   0ull                 // fp16 [M][H]: layer-0 input (f32->f16)
#define WS_XP   33554432ull          // fp16 [M][G]: layer-0 input projection, packed [m][cell][4]
#define WS_WI   167772160ull         // fp16 [L][G][H]
#define WS_WH   168820736ull         // fp16 [L][G][H]
#define WS_BSUM 169869312ull         // f32 [L][G]  (b_ih + b_hh)
#define WS_HP0  169877504ull         // u32 ring [B][RING_R][256] tagged h0
#define WS_HP1  170008576ull         // u32 ring [B][RING_R][256] tagged h1

__global__ void cvt_f32_f16(const float* __restrict__ in, half_t* __restrict__ out, int n){
  int i = blockIdx.x*256 + threadIdx.x;
  if (i < n) out[i] = (half_t)in[i];
}

__global__ void make_bsum(const float* __restrict__ bi, const float* __restrict__ bh,
                          float* __restrict__ bs, int n){
  int i = blockIdx.x*256 + threadIdx.x;
  if (i < n) bs[i] = bi[i] + bh[i];
}

// XP[m, cell, gate] = sum_k A[m,k] * W[gate*256+cell, k] + bsum[...]
__global__ __launch_bounds__(256) void gemm_xp(
    const half_t* __restrict__ A, const half_t* __restrict__ W,
    const float* __restrict__ bsum, half_t* __restrict__ XP)
{
  const int wave = threadIdx.x >> 6;
  const int lane = threadIdx.x & 63;
  const int l15 = lane & 15, quad = lane >> 4;
  const int m0 = blockIdx.x*64 + wave*16;
  const int n0 = blockIdx.y*64;
  float4_t acc[4] = {{0,0,0,0},{0,0,0,0},{0,0,0,0},{0,0,0,0}};
  const half_t* arow = A + (size_t)(m0 + l15)*H_N + quad*8;
  const half_t* brow[4];
  #pragma unroll
  for (int nt=0; nt<4; ++nt)
    brow[nt] = W + (size_t)(n0 + nt*16 + l15)*H_N + quad*8;
  #pragma unroll
  for (int k0=0; k0<H_N; k0+=32){
    half8_t af = *(const half8_t*)(arow + k0);
    #pragma unroll
    for (int nt=0; nt<4; ++nt){
      half8_t bf = *(const half8_t*)(brow[nt] + k0);
      acc[nt] = __builtin_amdgcn_mfma_f32_16x16x32_f16(af, bf, acc[nt], 0, 0, 0);
    }
  }
  #pragma unroll
  for (int nt=0; nt<4; ++nt){
    const int col = n0 + nt*16 + l15;          // gate row g in [0,1024)
    const int cell = col & 255, gate = col >> 8;
    const float bs = bsum[col];
    #pragma unroll
    for (int r=0; r<4; ++r){
      XP[(size_t)(m0 + quad*4 + r)*G_N + cell*4 + gate] = (half_t)(acc[nt][r] + bs);
    }
  }
}

__device__ __forceinline__ float sigf(float x){ return 1.f/(1.f + __expf(-x)); }
__device__ __forceinline__ float tanh_f(float x){ return 1.f - 2.f/(__expf(2.f*x) + 1.f); }

__device__ __forceinline__ unsigned ld32a(const unsigned* p){
  return __hip_atomic_load(p, __ATOMIC_RELAXED, __HIP_MEMORY_SCOPE_AGENT);
}
__device__ __forceinline__ void st32a(unsigned* p, unsigned v){
  __hip_atomic_store(p, v, __ATOMIC_RELAXED, __HIP_MEMORY_SCOPE_AGENT);
}

__device__ __forceinline__ void dot2(float& a, uint32_t w, uint32_t h){
  a = __builtin_amdgcn_fdot2(__builtin_bit_cast(half2_t, w),
                             __builtin_bit_cast(half2_t, h), a, false);
}

// Raw LDS-only barrier (no vmcnt drain of in-flight global ops) - r4 proven.
__device__ __forceinline__ void wg_barrier_lds(){
  asm volatile("s_waitcnt lgkmcnt(0)" ::: "memory");
  __builtin_amdgcn_s_barrier();
  asm volatile("" ::: "memory");
}

// Ring protocol (r4-proven): u32 atom {tag16|fp16}; tags = step+1 (L0) / step
// (L1), nonzero vs memset-0 init, <=2049 fits 16 bits; 4 slots with lockstep
// skew <=1 (iteration t requires ALL peers' iteration t-1 publishes) -> slot
// reuse distance 4 never collides with a lagging reader (distance 2).
// Double-buffered LDS h: buffer p=t&1 read at iter t; written (foreign by
// pollers at stage(t), own by finishers at end of iter t-1) strictly between
// B1(t-1) and B1(t) -> single barrier per iteration suffices for both RAW and
// WAR (readers of p at iter t-2 finished before B1(t-1)).
__global__ __launch_bounds__(768,3) void lstm_fused(
    const uint32_t* __restrict__ Wh0,  // fp16-pair view [1024][128] layer0 Whh
    const uint32_t* __restrict__ Wh1,  // layer1 Whh
    const uint32_t* __restrict__ Wi1,  // layer1 Wih
    const half_t*  __restrict__ xp,    // [M][1024] packed [m][cell][4], biases folded
    const float*   __restrict__ bsum1, // [1024] layer1 bias sums
    unsigned* __restrict__ hp0,
    unsigned* __restrict__ hp1,
    float* __restrict__ out,           // [B][S][H] fp32 layer1 h sequence
    float* __restrict__ hT, float* __restrict__ cT)
{
  __shared__ __align__(16) uint32_t h0buf[2][128];  // h pairs, u16[256] view
  __shared__ __align__(16) uint32_t h1buf[2][128];
  const int tid = threadIdx.x;
  const int wv  = tid >> 6;
  const int ln  = tid & 63;
  const int b   = blockIdx.x & 31;
  const int s   = blockIdx.x >> 5;
  const bool isL0 = (wv < 4);

  // lane -> (cell, gate, K-chunk)
  const int c_loc = isL0 ? (ln >> 3) : (ln >> 4);
  const int g     = isL0 ? ((ln >> 1) & 3) : ((ln >> 2) & 3);
  const int ksel  = isL0 ? (ln & 1) : (ln & 3);
  const int cell  = isL0 ? (s*32 + wv*8 + c_loc) : (s*32 + (wv-4)*4 + c_loc);
  const bool fin  = isL0 ? ((ln & 7) == 0) : ((ln & 15) == 0);

  // VGPR-resident weights: 64 pairs of row (g*256+cell) of my matrix chunk
  const uint32_t* mat; int koff;
  if (isL0)          { mat = Wh0; koff = ksel*64; }
  else if (ksel < 2) { mat = Wh1; koff = ksel*64; }
  else               { mat = Wi1; koff = (ksel-2)*64; }
  uint32_t w[64];
  {
    const uint32_t* wp = mat + (size_t)(g*256 + cell)*128 + koff;
    #pragma unroll
    for (int i=0;i<64;++i) w[i] = wp[i];
  }

  // L1 finisher biases
  float bb0=0.f, bb1=0.f, bb2=0.f, bb3=0.f;
  if (!isL0 && fin){
    bb0 = bsum1[      cell];
    bb1 = bsum1[256 + cell];
    bb2 = bsum1[512 + cell];
    bb3 = bsum1[768 + cell];
  }

  // poll roles: waves 0-3 (tid<224) poll the 224 foreign h0 cells; waves 4-7
  // (tid 256..479) poll foreign h1. Own 32 cells arrive via LDS, not rings.
  const int prole = (tid < 224) ? 0 : ((tid >= 256 && tid < 480) ? 1 : -1);
  const int pidx  = (prole == 1) ? tid - 256 : tid;
  const int pcell = (pidx < s*32) ? pidx : pidx + 32;   // skip own slice

  unsigned* r0 = hp0 + (size_t)b*(RING_R*256);
  unsigned* r1 = hp1 + (size_t)b*(RING_R*256);
  const size_t base = (size_t)b * S_N;
  float cst = 0.f;

  if (tid < 128){
    h0buf[0][tid] = 0u; h0buf[1][tid] = 0u;   // h0[-1] = 0
    h1buf[0][tid] = 0u; h1buf[1][tid] = 0u;   // h1[-1] = h1[-2] = 0
  }
  wg_barrier_lds();

  for (int t=0; t<=S_N; ++t){
    const int p = t & 1;
    // ---- stage foreign h into buffer p (r4-style dependent-load spin)
    if (prole == 0){
      if (t > 0){
        const unsigned* q = r0 + (size_t)((t-1)&(RING_R-1))*256 + pcell;
        unsigned v;
        do { v = ld32a(q); } while ((v >> 16) != (unsigned)t);
        ((unsigned short*)h0buf[p])[pcell] = (unsigned short)v;
      }
    } else if (prole == 1){
      if (t > 1){
        const unsigned* q = r1 + (size_t)((t-2)&(RING_R-1))*256 + pcell;
        unsigned v;
        do { v = ld32a(q); } while ((v >> 16) != (unsigned)(t-1));
        ((unsigned short*)h1buf[p])[pcell] = (unsigned short)v;
      }
    }
    // xp load for L0 finisher lanes (in flight across the barrier)
    uint2 xv = {0u,0u};
    if (isL0 && fin && t < S_N)
      xv = *(const uint2*)(xp + (base + t)*G_N + (size_t)cell*4);
    wg_barrier_lds();                  // B1: h staged (the ONLY barrier)

    const bool active = isL0 ? (t < S_N) : (t >= 1);
    if (active){
      // my 64 h pairs (wave-uniform broadcast reads per ksel group)
      const uint4* h4;
      if (isL0)          h4 = (const uint4*)(h0buf[p]) + ksel*16;
      else if (ksel < 2) h4 = (const uint4*)(h1buf[p]) + ksel*16;
      else               h4 = (const uint4*)(h0buf[p]) + (ksel-2)*16;
      float a0=0.f, a1=0.f, a2=0.f, a3=0.f;
      #pragma unroll
      for (int i=0;i<16;++i){
        const uint4 hh = h4[i];
        dot2(a0, w[4*i+0], hh.x);
        dot2(a1, w[4*i+1], hh.y);
        dot2(a2, w[4*i+2], hh.z);
        dot2(a3, w[4*i+3], hh.w);
      }
      float v = (a0+a1)+(a2+a3);
      // K-chunk reduce within the wave
      v += __shfl_xor(v, 1, 64);
      if (!isL0) v += __shfl_xor(v, 2, 64);
      // gather the 4 gate sums to the finisher lane of each cell group
      const int gb = isL0 ? (ln & ~7) : (ln & ~15);
      const int gs = isL0 ? 2 : 4;
      const float r0v = __shfl(v, gb,        64);
      const float r1v = __shfl(v, gb + gs,   64);
      const float r2v = __shfl(v, gb + 2*gs, 64);
      const float r3v = __shfl(v, gb + 3*gs, 64);
      if (fin){
        float s0, s1, s2, s3;
        if (isL0){
          const half2_t xlo = __builtin_bit_cast(half2_t, xv.x);
          const half2_t xhi = __builtin_bit_cast(half2_t, xv.y);
          s0 = r0v + (float)xlo.x;
          s1 = r1v + (float)xlo.y;
          s2 = r2v + (float)xhi.x;
          s3 = r3v + (float)xhi.y;
        } else {
          s0 = r0v + bb0; s1 = r1v + bb1; s2 = r2v + bb2; s3 = r3v + bb3;
        }
        const float gi = sigf(s0);
        const float gf = sigf(s1);
        const float gg = tanh_f(s2);
        const float go = sigf(s3);
        cst = gf*cst + gi*gg;
        const float h = go * tanh_f(cst);
        const unsigned hu = (unsigned)__builtin_bit_cast(unsigned short, (half_t)h);
        if (isL0){
          // publish FIRST (critical path), then own-cell LDS write
          st32a(r0 + (size_t)(t&(RING_R-1))*256 + cell,
                (((unsigned)(t+1)) << 16) | hu);
          ((unsigned short*)h0buf[p^1])[cell] = (unsigned short)hu;
          if (t == S_N-1){ hT[b*H_N + cell] = h; cT[b*H_N + cell] = cst; }
        } else {
          st32a(r1 + (size_t)((t-1)&(RING_R-1))*256 + cell,
                (((unsigned)t) << 16) | hu);
          ((unsigned short*)h1buf[p^1])[cell] = (unsigned short)hu;
          out[(base + (t-1))*H_N + cell] = h;
          if (t == S_N){ hT[B_N*H_N + b*H_N + cell] = h; cT[B_N*H_N + b*H_N + cell] = cst; }
        }
      }
    }
    // no second barrier: all buffer-(p^1) writes (own cells here, foreign by
    // pollers at stage(t+1)) are separated from that buffer's readers
    // (compute(t-1)) by B1(t); see protocol comment above.
  }
}

extern "C" void kernel_launch(void* const* d_in, const int* in_sizes, int n_in,
                              void* d_out, int out_size, void* d_ws, size_t ws_size,
                              hipStream_t stream)
{
  const float* x   = (const float*)d_in[0];
  const float* Wih = (const float*)d_in[1];
  const float* bih = (const float*)d_in[2];
  const float* Whh = (const float*)d_in[3];
  const float* bhh = (const float*)d_in[4];
  float* out = (float*)d_out;

  char* ws = (char*)d_ws;
  half_t* A0   = (half_t*)(ws + WS_A0);
  half_t* XP   = (half_t*)(ws + WS_XP);
  half_t* Wi16 = (half_t*)(ws + WS_WI);
  half_t* Wh16 = (half_t*)(ws + WS_WH);
  float*  bsum = (float*)(ws + WS_BSUM);
  unsigned* hp0 = (unsigned*)(ws + WS_HP0);
  unsigned* hp1 = (unsigned*)(ws + WS_HP1);

  cvt_f32_f16<<<dim3(M_N*H_N/256), dim3(256), 0, stream>>>(x, A0, M_N*H_N);
  cvt_f32_f16<<<dim3(L_N*G_N*H_N/256), dim3(256), 0, stream>>>(Wih, Wi16, L_N*G_N*H_N);
  cvt_f32_f16<<<dim3(L_N*G_N*H_N/256), dim3(256), 0, stream>>>(Whh, Wh16, L_N*G_N*H_N);
  make_bsum<<<dim3(L_N*G_N/256), dim3(256), 0, stream>>>(bih, bhh, bsum, L_N*G_N);

  float* hT = out + (size_t)M_N*H_N;       // hs [2][32][256]
  float* cT = hT + (size_t)L_N*B_N*H_N;    // cs [2][32][256]

  // layer-0 input projection (layer-1's is fused into the recurrence kernel)
  gemm_xp<<<dim3(M_N/64, G_N/64), dim3(256), 0, stream>>>(A0, Wi16, bsum, XP);

  hipMemsetAsync(hp0, 0, 2*RING_BYTES, stream);   // hp0 + hp1 contiguous

  lstm_fused<<<dim3(B_N*8), dim3(768), 0, stream>>>(
      (const uint32_t*)Wh16,
      (const uint32_t*)(Wh16 + (size_t)G_N*H_N),
      (const uint32_t*)(Wi16 + (size_t)G_N*H_N),
      XP, bsum + G_N, hp0, hp1, out, hT, cT);
}

// Round 11
// 4488.729 us; speedup vs baseline: 3.3112x; 1.6309x over previous
//
#include <hip/hip_runtime.h>
#include <cstdint>
#include <cstddef>

typedef _Float16 half_t;
typedef _Float16 half2_t __attribute__((ext_vector_type(2)));
typedef _Float16 half8_t __attribute__((ext_vector_type(8)));
typedef float   float4_t __attribute__((ext_vector_type(4)));

#define L_N 2
#define B_N 32
#define S_N 2048
#define H_N 256
#define G_N 1024            // 4H
#define M_N (B_N*S_N)       // 65536

// ---- fused recurrence geometry (r4 chassis, verbatim structure) ----
// 256 blocks = 32 chains x 8 cell-slices; iteration t advances layer0 step t
// and layer1 step t-1. 768 threads in 6 parts of 128:
// parts 0,1 = Wh0 K-halves; 2,3 = Wh1; 4,5 = Wi1 (fused layer-1 x-projection).
// r11 deltas vs r4 (minimal, mechanism-targeted):
//  (1) ring atom u32 {tag16|h fp16} -> finishers publish per-lane immediately
//      (no shuffle packing on the critical path); 512 poll lanes, 1 cell each.
//  (2) lookahead-1 poll in PLAIN HIP (r2-verified; no inline asm per r9):
//      next load issued before checking previous -> check period ~RTT/2.
// Everything else (broadcast LDS reads, red[] reduce, LDS-only barriers,
// split finishers, ring depth + WAR/skew arguments) identical to r4.
#define RING_R 4
#define RING_BYTES (B_N*RING_R*256*4)   // 128 KiB per ring (u32 per cell)

// ws layout (bytes)
#define WS_A0   0ull                 // fp16 [M][H]: layer-0 input (f32->f16)
#define WS_XP   33554432ull          // fp16 [M][G]: layer-0 input projection, packed [m][cell][4]
#define WS_WI   167772160ull         // fp16 [L][G][H]
#define WS_WH   168820736ull         // fp16 [L][G][H]
#define WS_BSUM 169869312ull         // f32 [L][G]  (b_ih + b_hh)
#define WS_HP0  169877504ull         // u32 ring [B][RING_R][256] tagged h0
#define WS_HP1  170008576ull         // u32 ring [B][RING_R][256] tagged h1

__global__ void cvt_f32_f16(const float* __restrict__ in, half_t* __restrict__ out, int n){
  int i = blockIdx.x*256 + threadIdx.x;
  if (i < n) out[i] = (half_t)in[i];
}

__global__ void make_bsum(const float* __restrict__ bi, const float* __restrict__ bh,
                          float* __restrict__ bs, int n){
  int i = blockIdx.x*256 + threadIdx.x;
  if (i < n) bs[i] = bi[i] + bh[i];
}

// XP[m, cell, gate] = sum_k A[m,k] * W[gate*256+cell, k] + bsum[...]
__global__ __launch_bounds__(256) void gemm_xp(
    const half_t* __restrict__ A, const half_t* __restrict__ W,
    const float* __restrict__ bsum, half_t* __restrict__ XP)
{
  const int wave = threadIdx.x >> 6;
  const int lane = threadIdx.x & 63;
  const int l15 = lane & 15, quad = lane >> 4;
  const int m0 = blockIdx.x*64 + wave*16;
  const int n0 = blockIdx.y*64;
  float4_t acc[4] = {{0,0,0,0},{0,0,0,0},{0,0,0,0},{0,0,0,0}};
  const half_t* arow = A + (size_t)(m0 + l15)*H_N + quad*8;
  const half_t* brow[4];
  #pragma unroll
  for (int nt=0; nt<4; ++nt)
    brow[nt] = W + (size_t)(n0 + nt*16 + l15)*H_N + quad*8;
  #pragma unroll
  for (int k0=0; k0<H_N; k0+=32){
    half8_t af = *(const half8_t*)(arow + k0);
    #pragma unroll
    for (int nt=0; nt<4; ++nt){
      half8_t bf = *(const half8_t*)(brow[nt] + k0);
      acc[nt] = __builtin_amdgcn_mfma_f32_16x16x32_f16(af, bf, acc[nt], 0, 0, 0);
    }
  }
  #pragma unroll
  for (int nt=0; nt<4; ++nt){
    const int col = n0 + nt*16 + l15;          // gate row g in [0,1024)
    const int cell = col & 255, gate = col >> 8;
    const float bs = bsum[col];
    #pragma unroll
    for (int r=0; r<4; ++r){
      XP[(size_t)(m0 + quad*4 + r)*G_N + cell*4 + gate] = (half_t)(acc[nt][r] + bs);
    }
  }
}

__device__ __forceinline__ float sigf(float x){ return 1.f/(1.f + __expf(-x)); }
__device__ __forceinline__ float tanh_f(float x){ return 1.f - 2.f/(__expf(2.f*x) + 1.f); }

__device__ __forceinline__ unsigned ld32a(const unsigned* p){
  return __hip_atomic_load(p, __ATOMIC_RELAXED, __HIP_MEMORY_SCOPE_AGENT);
}
__device__ __forceinline__ void st32a(unsigned* p, unsigned v){
  __hip_atomic_store(p, v, __ATOMIC_RELAXED, __HIP_MEMORY_SCOPE_AGENT);
}

// Lookahead-1 poll (plain HIP, r2-verified pattern): the next load is issued
// BEFORE the previous value is checked, so the compiler's counted vmcnt lets
// checks retire every ~half load-latency instead of every full round trip.
// Value+tag travel in one aligned u32 -> no torn reads, no ordering needed.
__device__ __forceinline__ unsigned poll_la(const unsigned* q, unsigned tag){
  unsigned a = ld32a(q);
  for (;;){
    unsigned b = ld32a(q);
    if ((a >> 16) == tag) return a;
    a = b;
  }
}

__device__ __forceinline__ void dot2(float& a, uint32_t w, uint32_t h){
  a = __builtin_amdgcn_fdot2(__builtin_bit_cast(half2_t, w),
                             __builtin_bit_cast(half2_t, h), a, false);
}

// Raw barrier: orders LDS staging across waves WITHOUT draining outstanding
// global stores/loads (r4-proven).
__device__ __forceinline__ void wg_barrier_lds(){
  asm volatile("s_waitcnt lgkmcnt(0)" ::: "memory");
  __builtin_amdgcn_s_barrier();
  asm volatile("" ::: "memory");
}

// Fused 2-layer LSTM recurrence (r4 protocol):
// 4-slot rings, lockstep skew <=1 (iter t needs ALL peers' iter t-1
// publishes) -> slot reuse distance 4 never collides; tags = step+1 (h0) /
// step (h1), nonzero vs memset-0 init, <=2049 fits 16 bits. WAR on
// h0s/h1s/red without trailing barrier: h-stage writers run after B2(t-1) in
// phase-1(t), readers finished before B2(t-1); red writers after B1(t),
// readers (finishers, phase-3(t-1)) finished before B1(t).
__global__ __launch_bounds__(768) void lstm_fused(
    const uint32_t* __restrict__ Wh0,  // fp16-pair view [1024][128] layer0 Whh
    const uint32_t* __restrict__ Wh1,  // layer1 Whh
    const uint32_t* __restrict__ Wi1,  // layer1 Wih
    const half_t*  __restrict__ xp,    // [M][1024] packed [m][cell][4], biases folded
    const float*   __restrict__ bsum1, // [1024] layer1 bias sums
    unsigned* __restrict__ hp0,
    unsigned* __restrict__ hp1,
    float* __restrict__ out,           // [B][S][H] fp32 layer1 h sequence
    float* __restrict__ hT, float* __restrict__ cT)
{
  __shared__ __align__(16) uint32_t h0s[128];  // h0[t-1], u16[256] view
  __shared__ __align__(16) uint32_t h1s[128];  // h1[t-2], u16[256] view
  __shared__ float red[6][128];
  const int tid = threadIdx.x;
  const int part = tid >> 7;       // 0..5
  const int r    = tid & 127;      // row in slice: gate g = r>>5, cell cl = r&31
  const int kh   = part & 1;       // K-half
  const int b  = blockIdx.x & 31;
  const int s  = blockIdx.x >> 5;
  const int g  = r >> 5;
  const int cl = r & 31;
  const int cell = s*32 + cl;

  // VGPR-resident weights: row (g*256+cell) of my matrix, pairs [kh*64, kh*64+64)
  const uint32_t* wbase =
      (part < 2 ? Wh0 : (part < 4 ? Wh1 : Wi1)) + (size_t)(g*256 + cell)*128 + kh*64;
  uint32_t w[64];
  #pragma unroll
  for (int i=0;i<64;++i) w[i] = wbase[i];

  // L1 finisher = wave1 lanes 0-31 (tid 64..95): biases + c-state
  float bb0=0.f, bb1=0.f, bb2=0.f, bb3=0.f;
  if (tid >= 64 && tid < 96){
    const int mc = s*32 + (tid - 64);
    bb0 = bsum1[      mc];
    bb1 = bsum1[256 + mc];
    bb2 = bsum1[512 + mc];
    bb3 = bsum1[768 + mc];
  }

  unsigned* r0 = hp0 + (size_t)b*(RING_R*256);
  unsigned* r1 = hp1 + (size_t)b*(RING_R*256);
  const size_t base = (size_t)b * S_N;
  float cst = 0.f;   // wave0 lanes0-31: layer0 c; wave1 lanes0-31: layer1 c

  for (int t=0; t<=S_N; ++t){
    // ---- phase 1: xp prefetch (wave0 lanes 0-31) + ring polls -> LDS stage
    uint2 xv = {0u,0u};
    if (tid < 32 && t < S_N)
      xv = *(const uint2*)(xp + (base + t)*G_N + (size_t)(s*32 + tid)*4);
    if (tid < 256){
      unsigned hv = 0u;
      if (t > 0) hv = poll_la(r0 + (size_t)((t-1)&(RING_R-1))*256 + tid, (unsigned)t);
      ((unsigned short*)h0s)[tid] = (unsigned short)hv;   // 2-way same-dword: free
    } else if (tid < 512){
      const int j2 = tid - 256;
      unsigned hv = 0u;
      if (t > 1) hv = poll_la(r1 + (size_t)((t-2)&(RING_R-1))*256 + j2, (unsigned)(t-1));
      ((unsigned short*)h1s)[j2] = (unsigned short)hv;
    }
    wg_barrier_lds();                   // B1: h staged (LDS-only barrier)

    // ---- phase 2: fdot (64 pair-MACs, 4 streams; wave-uniform broadcast reads)
    const bool active = (part < 2) ? (t < S_N) : (t >= 1);
    if (active){
      const uint32_t* hsrc = (part == 2 || part == 3) ? h1s : h0s;
      const uint4* h4 = (const uint4*)(hsrc + kh*64);
      float a0=0.f,a1=0.f,a2=0.f,a3=0.f;
      #pragma unroll
      for (int i=0;i<16;++i){
        const uint4 hh = h4[i];
        dot2(a0, w[4*i+0], hh.x);
        dot2(a1, w[4*i+1], hh.y);
        dot2(a2, w[4*i+2], hh.z);
        dot2(a3, w[4*i+3], hh.w);
      }
      red[part][r] = (a0+a1)+(a2+a3);
    }
    wg_barrier_lds();                   // B2: partials visible (LDS-only)

    // ---- phase 3a: wave0 lanes 0-31 finish layer0 step t
    if (tid < 32){
      if (t < S_N){
        const int l = tid;
        const half2_t xlo = __builtin_bit_cast(half2_t, xv.x);
        const half2_t xhi = __builtin_bit_cast(half2_t, xv.y);
        const float s0 = red[0][     l] + red[1][     l] + (float)xlo.x;
        const float s1 = red[0][32 + l] + red[1][32 + l] + (float)xlo.y;
        const float s2 = red[0][64 + l] + red[1][64 + l] + (float)xhi.x;
        const float s3 = red[0][96 + l] + red[1][96 + l] + (float)xhi.y;
        const float gi = sigf(s0);
        const float gf = sigf(s1);
        const float gg = tanh_f(s2);
        const float go = sigf(s3);
        cst = gf*cst + gi*gg;
        const float h = go * tanh_f(cst);
        const unsigned hu = (unsigned)__builtin_bit_cast(unsigned short, (half_t)h);
        // per-lane tagged publish: first instruction after h is ready
        st32a(r0 + (size_t)(t&(RING_R-1))*256 + cell, (((unsigned)(t+1)) << 16) | hu);
        if (t == S_N-1){ hT[b*H_N + cell] = h; cT[b*H_N + cell] = cst; }
      }
    }
    // ---- phase 3b: wave1 lanes 0-31 finish layer1 step t-1 (concurrent)
    else if (tid >= 64 && tid < 96){
      if (t >= 1){
        const int l = tid - 64;
        const float s0 = red[2][     l] + red[3][     l] + red[4][     l] + red[5][     l] + bb0;
        const float s1 = red[2][32 + l] + red[3][32 + l] + red[4][32 + l] + red[5][32 + l] + bb1;
        const float s2 = red[2][64 + l] + red[3][64 + l] + red[4][64 + l] + red[5][64 + l] + bb2;
        const float s3 = red[2][96 + l] + red[3][96 + l] + red[4][96 + l] + red[5][96 + l] + bb3;
        const float gi = sigf(s0);
        const float gf = sigf(s1);
        const float gg = tanh_f(s2);
        const float go = sigf(s3);
        cst = gf*cst + gi*gg;
        const float h = go * tanh_f(cst);
        const unsigned hu = (unsigned)__builtin_bit_cast(unsigned short, (half_t)h);
        st32a(r1 + (size_t)((t-1)&(RING_R-1))*256 + cell, (((unsigned)t) << 16) | hu);
        out[(base + (t-1))*H_N + cell] = h;
        if (t == S_N){ hT[B_N*H_N + b*H_N + cell] = h; cT[B_N*H_N + b*H_N + cell] = cst; }
      }
    }
    // no trailing barrier (WAR argument unchanged from r4)
  }
}

extern "C" void kernel_launch(void* const* d_in, const int* in_sizes, int n_in,
                              void* d_out, int out_size, void* d_ws, size_t ws_size,
                              hipStream_t stream)
{
  const float* x   = (const float*)d_in[0];
  const float* Wih = (const float*)d_in[1];
  const float* bih = (const float*)d_in[2];
  const float* Whh = (const float*)d_in[3];
  const float* bhh = (const float*)d_in[4];
  float* out = (float*)d_out;

  char* ws = (char*)d_ws;
  half_t* A0   = (half_t*)(ws + WS_A0);
  half_t* XP   = (half_t*)(ws + WS_XP);
  half_t* Wi16 = (half_t*)(ws + WS_WI);
  half_t* Wh16 = (half_t*)(ws + WS_WH);
  float*  bsum = (float*)(ws + WS_BSUM);
  unsigned* hp0 = (unsigned*)(ws + WS_HP0);
  unsigned* hp1 = (unsigned*)(ws + WS_HP1);

  cvt_f32_f16<<<dim3(M_N*H_N/256), dim3(256), 0, stream>>>(x, A0, M_N*H_N);
  cvt_f32_f16<<<dim3(L_N*G_N*H_N/256), dim3(256), 0, stream>>>(Wih, Wi16, L_N*G_N*H_N);
  cvt_f32_f16<<<dim3(L_N*G_N*H_N/256), dim3(256), 0, stream>>>(Whh, Wh16, L_N*G_N*H_N);
  make_bsum<<<dim3(L_N*G_N/256), dim3(256), 0, stream>>>(bih, bhh, bsum, L_N*G_N);

  float* hT = out + (size_t)M_N*H_N;       // hs [2][32][256]
  float* cT = hT + (size_t)L_N*B_N*H_N;    // cs [2][32][256]

  // layer-0 input projection (layer-1's is fused into the recurrence kernel)
  gemm_xp<<<dim3(M_N/64, G_N/64), dim3(256), 0, stream>>>(A0, Wi16, bsum, XP);

  hipMemsetAsync(hp0, 0, 2*RING_BYTES, stream);   // hp0 + hp1 contiguous

  lstm_fused<<<dim3(B_N*8), dim3(768), 0, stream>>>(
      (const uint32_t*)Wh16,
      (const uint32_t*)(Wh16 + (size_t)G_N*H_N),
      (const uint32_t*)(Wi16 + (size_t)G_N*H_N),
      XP, bsum + G_N, hp0, hp1, out, hT, cT);
}